// Round 1
// baseline (2109.533 us; speedup 1.0000x reference)
//
#include <hip/hip_runtime.h>

#define HW   4096
#define DIM  256
#define NB   8

typedef short bf16x8 __attribute__((ext_vector_type(8)));
typedef short s16x4  __attribute__((ext_vector_type(4)));
typedef float f32x4  __attribute__((ext_vector_type(4)));
typedef float f32x16 __attribute__((ext_vector_type(16)));
typedef float f32x4v __attribute__((ext_vector_type(4)));

// round-to-nearest-even split of fp32 into bf16 hi + bf16 lo
__device__ __forceinline__ void split_bf16(float x, short& hi, short& lo) {
    unsigned u  = __builtin_bit_cast(unsigned, x);
    unsigned rh = (u + 0x7FFFu + ((u >> 16) & 1u)) >> 16;
    hi = (short)rh;
    float hf  = __builtin_bit_cast(float, rh << 16);
    float rem = x - hf;
    unsigned u2 = __builtin_bit_cast(unsigned, rem);
    unsigned rl = (u2 + 0x7FFFu + ((u2 >> 16) & 1u)) >> 16;
    lo = (short)rl;
}

__device__ __forceinline__ f32x4 mfma16(bf16x8 a, bf16x8 b, f32x4 c) {
    return __builtin_amdgcn_mfma_f32_16x16x32_bf16(a, b, c, 0, 0, 0);
}
__device__ __forceinline__ f32x16 mfma32(bf16x8 a, bf16x8 b, f32x16 c) {
    return __builtin_amdgcn_mfma_f32_32x32x16_bf16(a, b, c, 0, 0, 0);
}

// ---------------------------------------------------------------------------
// Kernel 1: per-column (k) softmax stats over the q axis.
// grid (64 k-tiles, 8 b), block 256. Computes m_k = max_q s(q,k),
// il_k = 1/sum_q exp(s-m). S^T = K^T Q via 16x16x32 bf16 MFMA, split-bf16 x3.
// ---------------------------------------------------------------------------
extern "C" __global__ void __launch_bounds__(256, 1)
k_stats(const float* __restrict__ K, const float* __restrict__ Q,
        float* __restrict__ m_out, float* __restrict__ il_out)
{
    __shared__ __attribute__((aligned(16))) short KtH[64][264];
    __shared__ __attribute__((aligned(16))) short KtL[64][264];
    __shared__ __attribute__((aligned(16))) short QtH[32][264];
    __shared__ __attribute__((aligned(16))) short QtL[32][264];

    const int b    = blockIdx.y;
    const int k0   = blockIdx.x * 64;
    const int t    = threadIdx.x;
    const int lane = t & 63;
    const int w    = t >> 6;        // wave 0..3 -> k rows w*16..w*16+15
    const int g    = lane >> 4;     // 0..3
    const int lq   = lane & 15;

    const float* __restrict__ Kb = K + (size_t)b * DIM * HW;
    const float* __restrict__ Qb = Q + (size_t)b * DIM * HW;

    // stage K tile: [256 d][64 k] -> transposed split-bf16 Kt[k][d]
    {
        const int kk = t & 63;
        const int d0 = t >> 6;      // 0..3
        #pragma unroll 4
        for (int pass = 0; pass < 64; ++pass) {
            int d = d0 + pass * 4;
            float x = Kb[(size_t)d * HW + k0 + kk];
            short h, l; split_bf16(x, h, l);
            KtH[kk][d] = h; KtL[kk][d] = l;
        }
    }

    float mr[4], lr[4];
    #pragma unroll
    for (int r = 0; r < 4; ++r) { mr[r] = -3.0e38f; lr[r] = 0.0f; }

    for (int q0 = 0; q0 < HW; q0 += 32) {
        __syncthreads();
        {   // stage Q tile [256 d][32 q] -> Qt[q][d]
            const int qq = t & 31;
            const int d0 = t >> 5;  // 0..7
            #pragma unroll 4
            for (int pass = 0; pass < 32; ++pass) {
                int d = d0 + pass * 8;
                float x = Qb[(size_t)d * HW + q0 + qq];
                short h, l; split_bf16(x, h, l);
                QtH[qq][d] = h; QtL[qq][d] = l;
            }
        }
        __syncthreads();

        #pragma unroll
        for (int qt = 0; qt < 2; ++qt) {
            f32x4 acc = {0.f, 0.f, 0.f, 0.f};
            #pragma unroll
            for (int ds = 0; ds < 8; ++ds) {
                const int dof = ds * 32 + g * 8;
                bf16x8 ah = *(const bf16x8*)&KtH[w * 16 + lq][dof];
                bf16x8 al = *(const bf16x8*)&KtL[w * 16 + lq][dof];
                bf16x8 bh = *(const bf16x8*)&QtH[qt * 16 + lq][dof];
                bf16x8 bl = *(const bf16x8*)&QtL[qt * 16 + lq][dof];
                acc = mfma16(ah, bh, acc);
                acc = mfma16(ah, bl, acc);
                acc = mfma16(al, bh, acc);
            }
            // D frag: row k = g*4+r (within wave's 16-k tile), col q = lq
            #pragma unroll
            for (int r = 0; r < 4; ++r) {
                float s = acc[r];
                if (s > mr[r]) {
                    lr[r] = lr[r] * __expf(mr[r] - s) + 1.0f;
                    mr[r] = s;
                } else {
                    lr[r] += __expf(s - mr[r]);
                }
            }
        }
    }

    // combine across the 16 lanes (different q) holding the same k rows
    #pragma unroll
    for (int r = 0; r < 4; ++r) {
        float m = mr[r], l = lr[r];
        #pragma unroll
        for (int off = 1; off < 16; off <<= 1) {
            float m2 = __shfl_xor(m, off);
            float l2 = __shfl_xor(l, off);
            float mn = fmaxf(m, m2);
            l = l * __expf(m - mn) + l2 * __expf(m2 - mn);
            m = mn;
        }
        if (lq == 0) {
            int kg = k0 + w * 16 + g * 4 + r;
            m_out[b * HW + kg]  = m;
            il_out[b * HW + kg] = 1.0f / l;
        }
    }
}

// ---------------------------------------------------------------------------
// Kernel 2: out[b,v,q] = sum_k exp(s(q,k)-m_k)*il_k * V[b,v,k]
// grid (64 q-tiles, 8 b), block 256. Per WG: q-tile 64, full v=256.
// S^T recomputed bitwise-identically to k_stats; PV via 32x32x16 MFMA.
// ---------------------------------------------------------------------------
extern "C" __global__ void __launch_bounds__(256, 1)
k_attn_out(const float* __restrict__ K, const float* __restrict__ Q,
           const float* __restrict__ V,
           const float* __restrict__ m_in, const float* __restrict__ il_in,
           float* __restrict__ out)
{
    __shared__ __attribute__((aligned(16))) short QtH[64][264];
    __shared__ __attribute__((aligned(16))) short QtL[64][264];
    __shared__ __attribute__((aligned(16))) short KtH[32][264];
    __shared__ __attribute__((aligned(16))) short KtL[32][264];
    __shared__ __attribute__((aligned(16))) short PtH[64][40];
    __shared__ __attribute__((aligned(16))) short PtL[64][40];

    const int b    = blockIdx.y;
    const int q0   = blockIdx.x * 64;
    const int t    = threadIdx.x;
    const int lane = t & 63;
    const int w    = t >> 6;        // wave id
    const int g    = lane >> 4;     // 16x16 frag group
    const int lq   = lane & 15;
    const int g2   = lane >> 5;     // 32x32 frag group
    const int l32  = lane & 31;

    const float* __restrict__ Kb  = K + (size_t)b * DIM * HW;
    const float* __restrict__ Qb  = Q + (size_t)b * DIM * HW;
    const float* __restrict__ Vb  = V + (size_t)b * DIM * HW;
    const float* __restrict__ mB  = m_in  + b * HW;
    const float* __restrict__ ilB = il_in + b * HW;

    // stage Q tile (resident): [256 d][64 q] -> Qt[q][d]
    {
        const int qq = t & 63;
        const int d0 = t >> 6;
        #pragma unroll 4
        for (int pass = 0; pass < 64; ++pass) {
            int d = d0 + pass * 4;
            float x = Qb[(size_t)d * HW + q0 + qq];
            short h, l; split_bf16(x, h, l);
            QtH[qq][d] = h; QtL[qq][d] = l;
        }
    }

    // acc[mt][qt]: wave w owns v rows [w*64, w*64+64), all 64 q
    f32x16 acc[2][2];
    #pragma unroll
    for (int i = 0; i < 2; ++i)
        #pragma unroll
        for (int j = 0; j < 2; ++j)
            #pragma unroll
            for (int e = 0; e < 16; ++e) acc[i][j][e] = 0.0f;

    for (int k0 = 0; k0 < HW; k0 += 32) {
        __syncthreads();
        {   // stage K tile [256 d][32 k] -> Kt[k][d]
            const int kk = t & 31;
            const int d0 = t >> 5;
            #pragma unroll 4
            for (int pass = 0; pass < 32; ++pass) {
                int d = d0 + pass * 8;
                float x = Kb[(size_t)d * HW + k0 + kk];
                short h, l; split_bf16(x, h, l);
                KtH[kk][d] = h; KtL[kk][d] = l;
            }
        }
        __syncthreads();

        // S^T[32k x 16q(wave)] : A = K^T rows, B = Q cols (wave w -> q w*16+lq)
        f32x4 sacc[2];
        #pragma unroll
        for (int kt = 0; kt < 2; ++kt) {
            f32x4 z = {0.f, 0.f, 0.f, 0.f};
            sacc[kt] = z;
        }
        #pragma unroll
        for (int ds = 0; ds < 8; ++ds) {
            const int dof = ds * 32 + g * 8;
            bf16x8 bh = *(const bf16x8*)&QtH[w * 16 + lq][dof];
            bf16x8 bl = *(const bf16x8*)&QtL[w * 16 + lq][dof];
            #pragma unroll
            for (int kt = 0; kt < 2; ++kt) {
                bf16x8 ah = *(const bf16x8*)&KtH[kt * 16 + lq][dof];
                bf16x8 al = *(const bf16x8*)&KtL[kt * 16 + lq][dof];
                sacc[kt] = mfma16(ah, bh, sacc[kt]);
                sacc[kt] = mfma16(ah, bl, sacc[kt]);
                sacc[kt] = mfma16(al, bh, sacc[kt]);
            }
        }

        // p = exp(s - m_k) * il_k ; write split-bf16 P^T to LDS Pt[q][k]
        {
            const int qc = w * 16 + lq;
            #pragma unroll
            for (int kt = 0; kt < 2; ++kt) {
                s16x4 ph, pl;
                #pragma unroll
                for (int r = 0; r < 4; ++r) {
                    int kg = k0 + kt * 16 + g * 4 + r;
                    float p = __expf(sacc[kt][r] - mB[kg]) * ilB[kg];
                    short h, l; split_bf16(p, h, l);
                    ph[r] = h; pl[r] = l;
                }
                *(s16x4*)&PtH[qc][kt * 16 + g * 4] = ph;
                *(s16x4*)&PtL[qc][kt * 16 + g * 4] = pl;
            }
        }
        __syncthreads();

        // PV: D[v32][q32] = V[v][k] * P^T[k][q], 32x32x16, kc steps of 16
        #pragma unroll
        for (int kc = 0; kc < 2; ++kc) {
            bf16x8 pbh[2], pbl[2];
            #pragma unroll
            for (int qt = 0; qt < 2; ++qt) {
                pbh[qt] = *(const bf16x8*)&PtH[qt * 32 + l32][kc * 16 + g2 * 8];
                pbl[qt] = *(const bf16x8*)&PtL[qt * 32 + l32][kc * 16 + g2 * 8];
            }
            #pragma unroll
            for (int mt = 0; mt < 2; ++mt) {
                const int v = w * 64 + mt * 32 + l32;
                const float* vp = Vb + (size_t)v * HW + k0 + kc * 16 + g2 * 8;
                f32x4v x0 = *(const f32x4v*)vp;
                f32x4v x1 = *(const f32x4v*)(vp + 4);
                bf16x8 ah, al;
                #pragma unroll
                for (int j = 0; j < 4; ++j) {
                    short h, l;
                    split_bf16(x0[j], h, l); ah[j] = h;     al[j] = l;
                    split_bf16(x1[j], h, l); ah[4 + j] = h; al[4 + j] = l;
                }
                #pragma unroll
                for (int qt = 0; qt < 2; ++qt) {
                    acc[mt][qt] = mfma32(ah, pbh[qt], acc[mt][qt]);
                    acc[mt][qt] = mfma32(ah, pbl[qt], acc[mt][qt]);
                    acc[mt][qt] = mfma32(al, pbh[qt], acc[mt][qt]);
                }
            }
        }
    }

    // epilogue: D col = q = l32 (+qt*32), row v = (r&3)+8*(r>>2)+4*g2 (+mt*32)
    float* __restrict__ ob = out + (size_t)b * DIM * HW;
    #pragma unroll
    for (int mt = 0; mt < 2; ++mt)
        #pragma unroll
        for (int qt = 0; qt < 2; ++qt)
            #pragma unroll
            for (int r = 0; r < 16; ++r) {
                int v = w * 64 + mt * 32 + (r & 3) + 8 * (r >> 2) + 4 * g2;
                int q = q0 + qt * 32 + l32;
                ob[(size_t)v * HW + q] = acc[mt][qt][r];
            }
}

extern "C" void kernel_launch(void* const* d_in, const int* in_sizes, int n_in,
                              void* d_out, int out_size, void* d_ws, size_t ws_size,
                              hipStream_t stream)
{
    (void)in_sizes; (void)n_in; (void)out_size; (void)ws_size;
    const float* K = (const float*)d_in[0];
    const float* Q = (const float*)d_in[1];
    const float* V = (const float*)d_in[2];
    float* m_ws  = (float*)d_ws;            // NB*HW floats
    float* il_ws = m_ws + (size_t)NB * HW;  // NB*HW floats

    dim3 blk(256);
    dim3 grid(64, NB);
    k_stats<<<grid, blk, 0, stream>>>(K, Q, m_ws, il_ws);
    k_attn_out<<<grid, blk, 0, stream>>>(K, Q, V, m_ws, il_ws, (float*)d_out);
}

// Round 2
// 733.693 us; speedup vs baseline: 2.8752x; 2.8752x over previous
//
#include <hip/hip_runtime.h>

#define HW   4096
#define DIM  256
#define NB   8

typedef short bf16x8 __attribute__((ext_vector_type(8)));
typedef short s16x4  __attribute__((ext_vector_type(4)));
typedef float f32x4  __attribute__((ext_vector_type(4)));
typedef float f32x16 __attribute__((ext_vector_type(16)));
typedef unsigned int u32;
typedef unsigned int u32_g __attribute__((address_space(1)));
typedef unsigned int u32_l __attribute__((address_space(3)));

// round-to-nearest-even split of fp32 into bf16 hi + bf16 lo
__device__ __forceinline__ void split_bf16(float x, short& hi, short& lo) {
    unsigned u  = __builtin_bit_cast(unsigned, x);
    unsigned rh = (u + 0x7FFFu + ((u >> 16) & 1u)) >> 16;
    hi = (short)rh;
    float hf  = __builtin_bit_cast(float, rh << 16);
    float rem = x - hf;
    unsigned u2 = __builtin_bit_cast(unsigned, rem);
    unsigned rl = (u2 + 0x7FFFu + ((u2 >> 16) & 1u)) >> 16;
    lo = (short)rl;
}

__device__ __forceinline__ f32x4 mfma16(bf16x8 a, bf16x8 b, f32x4 c) {
    return __builtin_amdgcn_mfma_f32_16x16x32_bf16(a, b, c, 0, 0, 0);
}
__device__ __forceinline__ f32x16 mfma32(bf16x8 a, bf16x8 b, f32x16 c) {
    return __builtin_amdgcn_mfma_f32_32x32x16_bf16(a, b, c, 0, 0, 0);
}

__device__ __forceinline__ void gload16(const void* g, void* l) {
    __builtin_amdgcn_global_load_lds((const u32_g*)g, (u32_l*)l, 16, 0, 0);
}

// ===========================================================================
// NEW PATH
// ===========================================================================

// pass0_T: X[b][256][4096] f32 -> XT_hi/lo[b][4096][256] bf16-shorts,
// each 512-B output row byte-swizzled: colbyte ^= ((row&7)<<4)
extern "C" __global__ void __launch_bounds__(256)
pass0_T(const float* __restrict__ src, short* __restrict__ dsth,
        short* __restrict__ dstl)
{
    __shared__ __attribute__((aligned(16))) short TH[16][264];
    __shared__ __attribute__((aligned(16))) short TL[16][264];
    const int b   = blockIdx.y;
    const int hw0 = blockIdx.x * 16;
    const int t   = threadIdx.x;
    const float* sb = src + (size_t)b * DIM * HW;

    {
        const int rl = t & 15;     // hw within tile
        const int dl = t >> 4;     // d base
        #pragma unroll
        for (int dp = 0; dp < 16; ++dp) {
            int d = dl + dp * 16;
            float x = sb[(size_t)d * HW + hw0 + rl];
            short h, l; split_bf16(x, h, l);
            TH[rl][d] = h; TL[rl][d] = l;
        }
    }
    __syncthreads();

    const int r   = t >> 4;          // row (hw) in tile
    const int c0  = (t & 15) * 2;    // first 16-B chunk of 2
    const int swz = (r & 7) << 4;
    size_t rowbyte = ((size_t)b * HW + hw0 + r) * (size_t)(DIM * 2);
    char* dh = (char*)dsth + rowbyte;
    char* dl = (char*)dstl + rowbyte;
    #pragma unroll
    for (int j = 0; j < 2; ++j) {
        int cb  = (c0 + j) * 16;
        int cbs = cb ^ swz;
        *(f32x4*)(dh + cbs) = *(const f32x4*)((const char*)&TH[r][0] + cb);
        *(f32x4*)(dl + cbs) = *(const f32x4*)((const char*)&TL[r][0] + cb);
    }
}

// pass0_V: V[b][256][4096] f32 -> V2[b][512 segs][256 v][8 hi + 8 lo] shorts
extern "C" __global__ void __launch_bounds__(256)
pass0_V(const float* __restrict__ V, short* __restrict__ v2)
{
    const int b = blockIdx.y, v = blockIdx.x, t = threadIdx.x;
    const float* sv = V + ((size_t)b * DIM + v) * HW + t * 16;
    #pragma unroll
    for (int s = 0; s < 2; ++s) {
        f32x4 x0 = *(const f32x4*)(sv + s * 8);
        f32x4 x1 = *(const f32x4*)(sv + s * 8 + 4);
        s16x4 h0, l0, h1, l1;
        #pragma unroll
        for (int j = 0; j < 4; ++j) {
            short h, l;
            split_bf16(x0[j], h, l); h0[j] = h; l0[j] = l;
            split_bf16(x1[j], h, l); h1[j] = h; l1[j] = l;
        }
        short* dp = v2 + (((size_t)b * 512 + (size_t)(t * 2 + s)) * DIM + v) * 16;
        *(s16x4*)(dp + 0)  = h0;
        *(s16x4*)(dp + 4)  = h1;
        *(s16x4*)(dp + 8)  = l0;
        *(s16x4*)(dp + 12) = l1;
    }
}

// k2_stats: per-k-column online max / exp-sum over all q.
// grid (64 k-tiles, NB). K-frags in registers; Q double-buffered LDS.
extern "C" __global__ void __launch_bounds__(256, 2)
k2_stats(const short* __restrict__ KTh, const short* __restrict__ KTl,
         const short* __restrict__ QTh, const short* __restrict__ QTl,
         float* __restrict__ m_out, float* __restrict__ il_out)
{
    __shared__ __attribute__((aligned(16))) short QH[2][32][256];
    __shared__ __attribute__((aligned(16))) short QL[2][32][256];

    const int b    = blockIdx.y;
    const int k0b  = blockIdx.x * 64;
    const int t    = threadIdx.x;
    const int lane = t & 63;
    const int w    = t >> 6;
    const int g    = lane >> 4;
    const int lq   = lane & 15;

    // K fragments resident in registers (swizzled global reads)
    bf16x8 kh[8], kl[8];
    {
        const int krow = k0b + w * 16 + lq;
        const char* rh = (const char*)KTh + ((size_t)b * HW + krow) * 512;
        const char* rl = (const char*)KTl + ((size_t)b * HW + krow) * 512;
        const int swz = (lq & 7) << 4;
        #pragma unroll
        for (int ds = 0; ds < 8; ++ds) {
            int cb = (64 * ds + 16 * g) ^ swz;
            kh[ds] = *(const bf16x8*)(rh + cb);
            kl[ds] = *(const bf16x8*)(rl + cb);
        }
    }

    const char* qhbase = (const char*)QTh + (size_t)b * HW * 512;
    const char* qlbase = (const char*)QTl + (size_t)b * HW * 512;
    auto stage = [&](int bi, int q0) {
        #pragma unroll
        for (int j = 0; j < 4; ++j) {
            int c   = (j << 2) + w;            // 0..15 chunks of 1 KB
            int off = c * 1024 + lane * 16;
            gload16(qhbase + (size_t)q0 * 512 + off, (char*)&QH[bi][0][0] + c * 1024);
            gload16(qlbase + (size_t)q0 * 512 + off, (char*)&QL[bi][0][0] + c * 1024);
        }
    };

    float mr[4], lr[4];
    #pragma unroll
    for (int r = 0; r < 4; ++r) { mr[r] = -3.0e38f; lr[r] = 0.0f; }

    stage(0, 0);
    __syncthreads();

    for (int it = 0; it < 128; ++it) {
        const int cur = it & 1;
        if (it + 1 < 128) stage(cur ^ 1, (it + 1) * 32);

        #pragma unroll
        for (int qt = 0; qt < 2; ++qt) {
            const int qr = qt * 16 + lq;
            const char* bhr = (const char*)&QH[cur][qr][0];
            const char* blr = (const char*)&QL[cur][qr][0];
            const int swzq = (qr & 7) << 4;
            f32x4 acc = {0.f, 0.f, 0.f, 0.f};
            #pragma unroll
            for (int ds = 0; ds < 8; ++ds) {
                int cb = (64 * ds + 16 * g) ^ swzq;
                bf16x8 bh = *(const bf16x8*)(bhr + cb);
                bf16x8 bl = *(const bf16x8*)(blr + cb);
                acc = mfma16(kh[ds], bh, acc);
                acc = mfma16(kh[ds], bl, acc);
                acc = mfma16(kl[ds], bh, acc);
            }
            #pragma unroll
            for (int r = 0; r < 4; ++r) {
                float s = acc[r];
                if (s > mr[r]) {
                    lr[r] = lr[r] * __expf(mr[r] - s) + 1.0f;
                    mr[r] = s;
                } else {
                    lr[r] += __expf(s - mr[r]);
                }
            }
        }
        __syncthreads();
    }

    #pragma unroll
    for (int r = 0; r < 4; ++r) {
        float m = mr[r], l = lr[r];
        #pragma unroll
        for (int off = 1; off < 16; off <<= 1) {
            float m2 = __shfl_xor(m, off);
            float l2 = __shfl_xor(l, off);
            float mn = fmaxf(m, m2);
            l = l * __expf(m - mn) + l2 * __expf(m2 - mn);
            m = mn;
        }
        if (lq == 0) {
            int kg = k0b + w * 16 + g * 4 + r;
            m_out[b * HW + kg]  = m;
            il_out[b * HW + kg] = 1.0f / l;
        }
    }
}

// k2_out: out[b,v,q] = sum_k exp(s-m_k)*il_k * V[v,k].
// grid (64 q-tiles, NB). Q-frags in registers; K double-buffered LDS;
// Pt swizzled LDS; V fragments from pre-split global (coalesced).
extern "C" __global__ void __launch_bounds__(256, 2)
k2_out(const short* __restrict__ KTh, const short* __restrict__ KTl,
       const short* __restrict__ QTh, const short* __restrict__ QTl,
       const short* __restrict__ V2,
       const float* __restrict__ m_in, const float* __restrict__ il_in,
       float* __restrict__ out)
{
    __shared__ __attribute__((aligned(16))) short KH[2][32][256];
    __shared__ __attribute__((aligned(16))) short KL[2][32][256];
    __shared__ __attribute__((aligned(16))) short PH[64][32];
    __shared__ __attribute__((aligned(16))) short PL[64][32];

    const int b    = blockIdx.y;
    const int q0   = blockIdx.x * 64;
    const int t    = threadIdx.x;
    const int lane = t & 63;
    const int w    = t >> 6;
    const int g    = lane >> 4;
    const int lq   = lane & 15;
    const int g2   = lane >> 5;
    const int l32  = lane & 31;

    // Q fragments resident in registers
    bf16x8 qh[8], ql[8];
    {
        const int qrow = q0 + w * 16 + lq;
        const char* rh = (const char*)QTh + ((size_t)b * HW + qrow) * 512;
        const char* rl = (const char*)QTl + ((size_t)b * HW + qrow) * 512;
        const int swz = (lq & 7) << 4;
        #pragma unroll
        for (int ds = 0; ds < 8; ++ds) {
            int cb = (64 * ds + 16 * g) ^ swz;
            qh[ds] = *(const bf16x8*)(rh + cb);
            ql[ds] = *(const bf16x8*)(rl + cb);
        }
    }

    const char* khbase = (const char*)KTh + (size_t)b * HW * 512;
    const char* klbase = (const char*)KTl + (size_t)b * HW * 512;
    auto stage = [&](int bi, int k0) {
        #pragma unroll
        for (int j = 0; j < 4; ++j) {
            int c   = (j << 2) + w;
            int off = c * 1024 + lane * 16;
            gload16(khbase + (size_t)k0 * 512 + off, (char*)&KH[bi][0][0] + c * 1024);
            gload16(klbase + (size_t)k0 * 512 + off, (char*)&KL[bi][0][0] + c * 1024);
        }
    };

    f32x16 acc[2][2];
    #pragma unroll
    for (int i = 0; i < 2; ++i)
        #pragma unroll
        for (int j = 0; j < 2; ++j)
            #pragma unroll
            for (int e = 0; e < 16; ++e) acc[i][j][e] = 0.0f;

    const float* mB  = m_in  + b * HW;
    const float* ilB = il_in + b * HW;

    stage(0, 0);
    __syncthreads();

    for (int it = 0; it < 128; ++it) {
        const int cur = it & 1;
        const int k0  = it * 32;
        if (it + 1 < 128) stage(cur ^ 1, k0 + 32);

        // ---- S^T (bitwise identical to k2_stats' chain) ----
        f32x4 sacc[2];
        #pragma unroll
        for (int kt = 0; kt < 2; ++kt) { f32x4 z = {0.f,0.f,0.f,0.f}; sacc[kt] = z; }
        const int swzk = (lq & 7) << 4;    // (kt*16+lq)&7 == lq&7
        const char* ahr0 = (const char*)&KH[cur][lq][0];
        const char* ahr1 = (const char*)&KH[cur][16 + lq][0];
        const char* alr0 = (const char*)&KL[cur][lq][0];
        const char* alr1 = (const char*)&KL[cur][16 + lq][0];
        #pragma unroll
        for (int ds = 0; ds < 8; ++ds) {
            int cb = (64 * ds + 16 * g) ^ swzk;
            {
                bf16x8 ah = *(const bf16x8*)(ahr0 + cb);
                bf16x8 al = *(const bf16x8*)(alr0 + cb);
                sacc[0] = mfma16(ah, qh[ds], sacc[0]);
                sacc[0] = mfma16(ah, ql[ds], sacc[0]);
                sacc[0] = mfma16(al, qh[ds], sacc[0]);
            }
            {
                bf16x8 ah = *(const bf16x8*)(ahr1 + cb);
                bf16x8 al = *(const bf16x8*)(alr1 + cb);
                sacc[1] = mfma16(ah, qh[ds], sacc[1]);
                sacc[1] = mfma16(ah, ql[ds], sacc[1]);
                sacc[1] = mfma16(al, qh[ds], sacc[1]);
            }
        }

        // ---- P = exp(s - m_k) * il_k, split, swizzled Pt write ----
        {
            const int qc   = w * 16 + lq;
            const int pswz = ((qc >> 1) & 3) << 4;
            #pragma unroll
            for (int kt = 0; kt < 2; ++kt) {
                int kg = k0 + kt * 16 + g * 4;
                f32x4 m4  = *(const f32x4*)&mB[kg];
                f32x4 il4 = *(const f32x4*)&ilB[kg];
                s16x4 ph, pl;
                #pragma unroll
                for (int r = 0; r < 4; ++r) {
                    float p = __expf(sacc[kt][r] - m4[r]) * il4[r];
                    short h, l; split_bf16(p, h, l);
                    ph[r] = h; pl[r] = l;
                }
                int cb = (32 * kt + 8 * g) ^ pswz;
                *(s16x4*)((char*)&PH[0][0] + qc * 64 + cb) = ph;
                *(s16x4*)((char*)&PL[0][0] + qc * 64 + cb) = pl;
            }
        }
        __syncthreads();   // Pt visible; next K tile drained

        // ---- PV: D[v][q] += V[v][k] * P[k][q], 32x32x16 ----
        #pragma unroll
        for (int kc = 0; kc < 2; ++kc) {
            bf16x8 pbh[2], pbl[2];
            #pragma unroll
            for (int qt = 0; qt < 2; ++qt) {
                int prow = qt * 32 + l32;
                int cb = (32 * kc + 16 * g2) ^ (((prow >> 1) & 3) << 4);
                pbh[qt] = *(const bf16x8*)((const char*)&PH[0][0] + prow * 64 + cb);
                pbl[qt] = *(const bf16x8*)((const char*)&PL[0][0] + prow * 64 + cb);
            }
            const int seg = (k0 >> 3) + kc * 2 + g2;
            #pragma unroll
            for (int mt = 0; mt < 2; ++mt) {
                int v = w * 64 + mt * 32 + l32;
                const short* vp = V2 + (((size_t)b * 512 + seg) * DIM + v) * 16;
                bf16x8 vh = *(const bf16x8*)(vp);
                bf16x8 vl = *(const bf16x8*)(vp + 8);
                #pragma unroll
                for (int qt = 0; qt < 2; ++qt) {
                    acc[mt][qt] = mfma32(vh, pbh[qt], acc[mt][qt]);
                    acc[mt][qt] = mfma32(vh, pbl[qt], acc[mt][qt]);
                    acc[mt][qt] = mfma32(vl, pbh[qt], acc[mt][qt]);
                }
            }
        }
        __syncthreads();   // P readers done before next iteration's writes
    }

    float* ob = out + (size_t)b * DIM * HW;
    #pragma unroll
    for (int mt = 0; mt < 2; ++mt)
        #pragma unroll
        for (int qt = 0; qt < 2; ++qt)
            #pragma unroll
            for (int r = 0; r < 16; ++r) {
                int v = w * 64 + mt * 32 + (r & 3) + 8 * (r >> 2) + 4 * g2;
                int q = q0 + qt * 32 + l32;
                ob[(size_t)v * HW + q] = acc[mt][qt][r];
            }
}

// ===========================================================================
// FALLBACK PATH (round-1 passing kernels, used only if ws too small)
// ===========================================================================
extern "C" __global__ void __launch_bounds__(256, 1)
k_stats(const float* __restrict__ K, const float* __restrict__ Q,
        float* __restrict__ m_out, float* __restrict__ il_out)
{
    __shared__ __attribute__((aligned(16))) short KtH[64][264];
    __shared__ __attribute__((aligned(16))) short KtL[64][264];
    __shared__ __attribute__((aligned(16))) short QtH[32][264];
    __shared__ __attribute__((aligned(16))) short QtL[32][264];

    const int b = blockIdx.y, k0 = blockIdx.x * 64, t = threadIdx.x;
    const int lane = t & 63, w = t >> 6, g = lane >> 4, lq = lane & 15;
    const float* Kb = K + (size_t)b * DIM * HW;
    const float* Qb = Q + (size_t)b * DIM * HW;

    {
        const int kk = t & 63, d0 = t >> 6;
        #pragma unroll 4
        for (int pass = 0; pass < 64; ++pass) {
            int d = d0 + pass * 4;
            float x = Kb[(size_t)d * HW + k0 + kk];
            short h, l; split_bf16(x, h, l);
            KtH[kk][d] = h; KtL[kk][d] = l;
        }
    }
    float mr[4], lr[4];
    #pragma unroll
    for (int r = 0; r < 4; ++r) { mr[r] = -3.0e38f; lr[r] = 0.0f; }

    for (int q0 = 0; q0 < HW; q0 += 32) {
        __syncthreads();
        {
            const int qq = t & 31, d0 = t >> 5;
            #pragma unroll 4
            for (int pass = 0; pass < 32; ++pass) {
                int d = d0 + pass * 8;
                float x = Qb[(size_t)d * HW + q0 + qq];
                short h, l; split_bf16(x, h, l);
                QtH[qq][d] = h; QtL[qq][d] = l;
            }
        }
        __syncthreads();
        #pragma unroll
        for (int qt = 0; qt < 2; ++qt) {
            f32x4 acc = {0.f, 0.f, 0.f, 0.f};
            #pragma unroll
            for (int ds = 0; ds < 8; ++ds) {
                const int dof = ds * 32 + g * 8;
                bf16x8 ah = *(const bf16x8*)&KtH[w * 16 + lq][dof];
                bf16x8 al = *(const bf16x8*)&KtL[w * 16 + lq][dof];
                bf16x8 bh = *(const bf16x8*)&QtH[qt * 16 + lq][dof];
                bf16x8 bl = *(const bf16x8*)&QtL[qt * 16 + lq][dof];
                acc = mfma16(ah, bh, acc);
                acc = mfma16(ah, bl, acc);
                acc = mfma16(al, bh, acc);
            }
            #pragma unroll
            for (int r = 0; r < 4; ++r) {
                float s = acc[r];
                if (s > mr[r]) { lr[r] = lr[r] * __expf(mr[r] - s) + 1.0f; mr[r] = s; }
                else lr[r] += __expf(s - mr[r]);
            }
        }
    }
    #pragma unroll
    for (int r = 0; r < 4; ++r) {
        float m = mr[r], l = lr[r];
        #pragma unroll
        for (int off = 1; off < 16; off <<= 1) {
            float m2 = __shfl_xor(m, off), l2 = __shfl_xor(l, off);
            float mn = fmaxf(m, m2);
            l = l * __expf(m - mn) + l2 * __expf(m2 - mn);
            m = mn;
        }
        if (lq == 0) {
            int kg = k0 + w * 16 + g * 4 + r;
            m_out[b * HW + kg] = m;
            il_out[b * HW + kg] = 1.0f / l;
        }
    }
}

extern "C" __global__ void __launch_bounds__(256, 1)
k_attn_out(const float* __restrict__ K, const float* __restrict__ Q,
           const float* __restrict__ V,
           const float* __restrict__ m_in, const float* __restrict__ il_in,
           float* __restrict__ out)
{
    __shared__ __attribute__((aligned(16))) short QtH[64][264];
    __shared__ __attribute__((aligned(16))) short QtL[64][264];
    __shared__ __attribute__((aligned(16))) short KtH[32][264];
    __shared__ __attribute__((aligned(16))) short KtL[32][264];
    __shared__ __attribute__((aligned(16))) short PtH[64][40];
    __shared__ __attribute__((aligned(16))) short PtL[64][40];

    const int b = blockIdx.y, q0 = blockIdx.x * 64, t = threadIdx.x;
    const int lane = t & 63, w = t >> 6, g = lane >> 4, lq = lane & 15;
    const int g2 = lane >> 5, l32 = lane & 31;
    const float* Kb = K + (size_t)b * DIM * HW;
    const float* Qb = Q + (size_t)b * DIM * HW;
    const float* Vb = V + (size_t)b * DIM * HW;
    const float* mB = m_in + b * HW;
    const float* ilB = il_in + b * HW;

    {
        const int qq = t & 63, d0 = t >> 6;
        #pragma unroll 4
        for (int pass = 0; pass < 64; ++pass) {
            int d = d0 + pass * 4;
            float x = Qb[(size_t)d * HW + q0 + qq];
            short h, l; split_bf16(x, h, l);
            QtH[qq][d] = h; QtL[qq][d] = l;
        }
    }
    f32x16 acc[2][2];
    #pragma unroll
    for (int i = 0; i < 2; ++i)
        #pragma unroll
        for (int j = 0; j < 2; ++j)
            #pragma unroll
            for (int e = 0; e < 16; ++e) acc[i][j][e] = 0.0f;

    for (int k0 = 0; k0 < HW; k0 += 32) {
        __syncthreads();
        {
            const int kk = t & 31, d0 = t >> 5;
            #pragma unroll 4
            for (int pass = 0; pass < 32; ++pass) {
                int d = d0 + pass * 8;
                float x = Kb[(size_t)d * HW + k0 + kk];
                short h, l; split_bf16(x, h, l);
                KtH[kk][d] = h; KtL[kk][d] = l;
            }
        }
        __syncthreads();
        f32x4 sacc[2];
        #pragma unroll
        for (int kt = 0; kt < 2; ++kt) { f32x4 z = {0.f,0.f,0.f,0.f}; sacc[kt] = z; }
        #pragma unroll
        for (int ds = 0; ds < 8; ++ds) {
            const int dof = ds * 32 + g * 8;
            bf16x8 bh = *(const bf16x8*)&QtH[w * 16 + lq][dof];
            bf16x8 bl = *(const bf16x8*)&QtL[w * 16 + lq][dof];
            #pragma unroll
            for (int kt = 0; kt < 2; ++kt) {
                bf16x8 ah = *(const bf16x8*)&KtH[kt * 16 + lq][dof];
                bf16x8 al = *(const bf16x8*)&KtL[kt * 16 + lq][dof];
                sacc[kt] = mfma16(ah, bh, sacc[kt]);
                sacc[kt] = mfma16(ah, bl, sacc[kt]);
                sacc[kt] = mfma16(al, bh, sacc[kt]);
            }
        }
        {
            const int qc = w * 16 + lq;
            #pragma unroll
            for (int kt = 0; kt < 2; ++kt) {
                s16x4 ph, pl;
                #pragma unroll
                for (int r = 0; r < 4; ++r) {
                    int kg = k0 + kt * 16 + g * 4 + r;
                    float p = __expf(sacc[kt][r] - mB[kg]) * ilB[kg];
                    short h, l; split_bf16(p, h, l);
                    ph[r] = h; pl[r] = l;
                }
                *(s16x4*)&PtH[qc][kt * 16 + g * 4] = ph;
                *(s16x4*)&PtL[qc][kt * 16 + g * 4] = pl;
            }
        }
        __syncthreads();
        #pragma unroll
        for (int kc = 0; kc < 2; ++kc) {
            bf16x8 pbh[2], pbl[2];
            #pragma unroll
            for (int qt = 0; qt < 2; ++qt) {
                pbh[qt] = *(const bf16x8*)&PtH[qt * 32 + l32][kc * 16 + g2 * 8];
                pbl[qt] = *(const bf16x8*)&PtL[qt * 32 + l32][kc * 16 + g2 * 8];
            }
            #pragma unroll
            for (int mt = 0; mt < 2; ++mt) {
                const int v = w * 64 + mt * 32 + l32;
                const float* vp = Vb + (size_t)v * HW + k0 + kc * 16 + g2 * 8;
                f32x4 x0 = *(const f32x4*)vp;
                f32x4 x1 = *(const f32x4*)(vp + 4);
                bf16x8 ah, al;
                #pragma unroll
                for (int j = 0; j < 4; ++j) {
                    short h, l;
                    split_bf16(x0[j], h, l); ah[j] = h;     al[j] = l;
                    split_bf16(x1[j], h, l); ah[4 + j] = h; al[4 + j] = l;
                }
                #pragma unroll
                for (int qt = 0; qt < 2; ++qt) {
                    acc[mt][qt] = mfma32(ah, pbh[qt], acc[mt][qt]);
                    acc[mt][qt] = mfma32(ah, pbl[qt], acc[mt][qt]);
                    acc[mt][qt] = mfma32(al, pbh[qt], acc[mt][qt]);
                }
            }
        }
    }
    float* ob = out + (size_t)b * DIM * HW;
    #pragma unroll
    for (int mt = 0; mt < 2; ++mt)
        #pragma unroll
        for (int qt = 0; qt < 2; ++qt)
            #pragma unroll
            for (int r = 0; r < 16; ++r) {
                int v = w * 64 + mt * 32 + (r & 3) + 8 * (r >> 2) + 4 * g2;
                int q = q0 + qt * 32 + l32;
                ob[(size_t)v * HW + q] = acc[mt][qt][r];
            }
}

// ===========================================================================
extern "C" void kernel_launch(void* const* d_in, const int* in_sizes, int n_in,
                              void* d_out, int out_size, void* d_ws, size_t ws_size,
                              hipStream_t stream)
{
    (void)in_sizes; (void)n_in; (void)out_size;
    const float* K = (const float*)d_in[0];
    const float* Q = (const float*)d_in[1];
    const float* V = (const float*)d_in[2];

    char* wsb = (char*)d_ws;
    float* m_ws  = (float*)wsb;
    float* il_ws = m_ws + (size_t)NB * HW;

    const size_t planeElems = (size_t)NB * HW * DIM;   // shorts per plane
    const size_t statsBytes = 262144;
    const size_t need = statsBytes + planeElems * 2 * 4 /*KT,QT hi+lo*/
                                   + planeElems * 2 * 2 /*V2*/;

    dim3 blk(256);
    if (ws_size >= need) {
        short* KTh = (short*)(wsb + statsBytes);
        short* KTl = KTh + planeElems;
        short* QTh = KTl + planeElems;
        short* QTl = QTh + planeElems;
        short* V2  = QTl + planeElems;

        dim3 gT(HW / 16, NB);     // 256 x 8
        pass0_T<<<gT, blk, 0, stream>>>(K, KTh, KTl);
        pass0_T<<<gT, blk, 0, stream>>>(Q, QTh, QTl);
        dim3 gV(DIM, NB);         // 256 x 8
        pass0_V<<<gV, blk, 0, stream>>>(V, V2);

        dim3 gM(64, NB);
        k2_stats<<<gM, blk, 0, stream>>>(KTh, KTl, QTh, QTl, m_ws, il_ws);
        k2_out<<<gM, blk, 0, stream>>>(KTh, KTl, QTh, QTl, V2, m_ws, il_ws,
                                       (float*)d_out);
    } else {
        dim3 gM(64, NB);
        k_stats<<<gM, blk, 0, stream>>>(K, Q, m_ws, il_ws);
        k_attn_out<<<gM, blk, 0, stream>>>(K, Q, V, m_ws, il_ws, (float*)d_out);
    }
}

// Round 3
// 638.316 us; speedup vs baseline: 3.3048x; 1.1494x over previous
//
#include <hip/hip_runtime.h>

#define HW   4096
#define DIM  256
#define NB   8

typedef short bf16x8 __attribute__((ext_vector_type(8)));
typedef short s16x4  __attribute__((ext_vector_type(4)));
typedef float f32x4  __attribute__((ext_vector_type(4)));
typedef float f32x16 __attribute__((ext_vector_type(16)));
typedef unsigned int u32;
typedef unsigned int u32_g __attribute__((address_space(1)));
typedef unsigned int u32_l __attribute__((address_space(3)));

// round-to-nearest-even split of fp32 into bf16 hi + bf16 lo
__device__ __forceinline__ void split_bf16(float x, short& hi, short& lo) {
    unsigned u  = __builtin_bit_cast(unsigned, x);
    unsigned rh = (u + 0x7FFFu + ((u >> 16) & 1u)) >> 16;
    hi = (short)rh;
    float hf  = __builtin_bit_cast(float, rh << 16);
    float rem = x - hf;
    unsigned u2 = __builtin_bit_cast(unsigned, rem);
    unsigned rl = (u2 + 0x7FFFu + ((u2 >> 16) & 1u)) >> 16;
    lo = (short)rl;
}

__device__ __forceinline__ f32x4 mfma16(bf16x8 a, bf16x8 b, f32x4 c) {
    return __builtin_amdgcn_mfma_f32_16x16x32_bf16(a, b, c, 0, 0, 0);
}
__device__ __forceinline__ f32x16 mfma32(bf16x8 a, bf16x8 b, f32x16 c) {
    return __builtin_amdgcn_mfma_f32_32x32x16_bf16(a, b, c, 0, 0, 0);
}

__device__ __forceinline__ void gload16(const void* g, void* l) {
    __builtin_amdgcn_global_load_lds((const u32_g*)g, (u32_l*)l, 16, 0, 0);
}

// ===========================================================================
// pass0_T: X[b][256][4096] f32 -> XT_hi/lo[b][4096][256] bf16-shorts,
// each 512-B output row byte-swizzled: colbyte ^= ((row&7)<<4)
// ===========================================================================
extern "C" __global__ void __launch_bounds__(256)
pass0_T(const float* __restrict__ src, short* __restrict__ dsth,
        short* __restrict__ dstl)
{
    __shared__ __attribute__((aligned(16))) short TH[16][264];
    __shared__ __attribute__((aligned(16))) short TL[16][264];
    const int b   = blockIdx.y;
    const int hw0 = blockIdx.x * 16;
    const int t   = threadIdx.x;
    const float* sb = src + (size_t)b * DIM * HW;

    {
        const int rl = t & 15;     // hw within tile
        const int dl = t >> 4;     // d base
        #pragma unroll
        for (int dp = 0; dp < 16; ++dp) {
            int d = dl + dp * 16;
            float x = sb[(size_t)d * HW + hw0 + rl];
            short h, l; split_bf16(x, h, l);
            TH[rl][d] = h; TL[rl][d] = l;
        }
    }
    __syncthreads();

    const int r   = t >> 4;          // row (hw) in tile
    const int c0  = (t & 15) * 2;    // first 16-B chunk of 2
    const int swz = (r & 7) << 4;
    size_t rowbyte = ((size_t)b * HW + hw0 + r) * (size_t)(DIM * 2);
    char* dh = (char*)dsth + rowbyte;
    char* dl = (char*)dstl + rowbyte;
    #pragma unroll
    for (int j = 0; j < 2; ++j) {
        int cb  = (c0 + j) * 16;
        int cbs = cb ^ swz;
        *(f32x4*)(dh + cbs) = *(const f32x4*)((const char*)&TH[r][0] + cb);
        *(f32x4*)(dl + cbs) = *(const f32x4*)((const char*)&TL[r][0] + cb);
    }
}

// pass0_V: V[b][256][4096] f32 -> V2[b][512 segs][256 v][8 hi + 8 lo] shorts
extern "C" __global__ void __launch_bounds__(256)
pass0_V(const float* __restrict__ V, short* __restrict__ v2)
{
    const int b = blockIdx.y, v = blockIdx.x, t = threadIdx.x;
    const float* sv = V + ((size_t)b * DIM + v) * HW + t * 16;
    #pragma unroll
    for (int s = 0; s < 2; ++s) {
        f32x4 x0 = *(const f32x4*)(sv + s * 8);
        f32x4 x1 = *(const f32x4*)(sv + s * 8 + 4);
        s16x4 h0, l0, h1, l1;
        #pragma unroll
        for (int j = 0; j < 4; ++j) {
            short h, l;
            split_bf16(x0[j], h, l); h0[j] = h; l0[j] = l;
            split_bf16(x1[j], h, l); h1[j] = h; l1[j] = l;
        }
        short* dp = v2 + (((size_t)b * 512 + (size_t)(t * 2 + s)) * DIM + v) * 16;
        *(s16x4*)(dp + 0)  = h0;
        *(s16x4*)(dp + 4)  = h1;
        *(s16x4*)(dp + 8)  = l0;
        *(s16x4*)(dp + 12) = l1;
    }
}

// ===========================================================================
// k3_stats: per-k-column online max / exp-sum over all q.
// 512 threads, 8 waves x 16 k-rows = 128 k per block; 64-q tiles, dbuf LDS.
// grid: 1-D 256 blocks, id&7 = batch (XCD-aligned).
// ===========================================================================
extern "C" __global__ void __launch_bounds__(512, 2)
k3_stats(const short* __restrict__ KTh, const short* __restrict__ KTl,
         const short* __restrict__ QTh, const short* __restrict__ QTl,
         float* __restrict__ m_out, float* __restrict__ il_out)
{
    __shared__ __attribute__((aligned(16))) short QH[2][64][256];
    __shared__ __attribute__((aligned(16))) short QL[2][64][256];

    const int id   = blockIdx.x;
    const int b    = id & 7;
    const int k0b  = (id >> 3) * 128;
    const int t    = threadIdx.x;
    const int lane = t & 63;
    const int w    = t >> 6;        // 0..7 -> k rows k0b + w*16
    const int g    = lane >> 4;
    const int lq   = lane & 15;

    // K fragments resident in registers (swizzled global rows)
    bf16x8 kh[8], kl[8];
    {
        const int krow = k0b + w * 16 + lq;
        const char* rh = (const char*)KTh + ((size_t)b * HW + krow) * 512;
        const char* rl = (const char*)KTl + ((size_t)b * HW + krow) * 512;
        const int swz = (lq & 7) << 4;
        #pragma unroll
        for (int ds = 0; ds < 8; ++ds) {
            int cb = (64 * ds + 16 * g) ^ swz;
            kh[ds] = *(const bf16x8*)(rh + cb);
            kl[ds] = *(const bf16x8*)(rl + cb);
        }
    }

    const char* qhbase = (const char*)QTh + (size_t)b * HW * 512;
    const char* qlbase = (const char*)QTl + (size_t)b * HW * 512;
    auto stage = [&](int bi, int q0) {
        #pragma unroll
        for (int j = 0; j < 4; ++j) {
            int c = (j << 3) + w;              // 0..31 chunks of 1 KB
            int o = c * 1024;
            gload16(qhbase + (size_t)q0 * 512 + o + lane * 16,
                    (char*)&QH[bi][0][0] + o);
            gload16(qlbase + (size_t)q0 * 512 + o + lane * 16,
                    (char*)&QL[bi][0][0] + o);
        }
    };

    float mr[4], lr[4];
    #pragma unroll
    for (int r = 0; r < 4; ++r) { mr[r] = -3.0e38f; lr[r] = 0.0f; }

    stage(0, 0);
    __syncthreads();

    for (int it = 0; it < 64; ++it) {
        const int cur = it & 1;
        if (it + 1 < 64) stage(cur ^ 1, (it + 1) * 64);

        #pragma unroll
        for (int qt = 0; qt < 4; ++qt) {
            const int qr = qt * 16 + lq;
            const char* bhr = (const char*)&QH[cur][qr][0];
            const char* blr = (const char*)&QL[cur][qr][0];
            const int swzq = (qr & 7) << 4;
            f32x4 acc = {0.f, 0.f, 0.f, 0.f};
            __builtin_amdgcn_s_setprio(1);
            #pragma unroll
            for (int ds = 0; ds < 8; ++ds) {
                int cb = (64 * ds + 16 * g) ^ swzq;
                bf16x8 bh = *(const bf16x8*)(bhr + cb);
                bf16x8 bl = *(const bf16x8*)(blr + cb);
                acc = mfma16(kh[ds], bh, acc);
                acc = mfma16(kh[ds], bl, acc);
                acc = mfma16(kl[ds], bh, acc);
            }
            __builtin_amdgcn_s_setprio(0);
            #pragma unroll
            for (int r = 0; r < 4; ++r) {
                float s = acc[r];
                if (s > mr[r]) {
                    lr[r] = lr[r] * __expf(mr[r] - s) + 1.0f;
                    mr[r] = s;
                } else {
                    lr[r] += __expf(s - mr[r]);
                }
            }
        }
        __syncthreads();
    }

    #pragma unroll
    for (int r = 0; r < 4; ++r) {
        float m = mr[r], l = lr[r];
        #pragma unroll
        for (int off = 1; off < 16; off <<= 1) {
            float m2 = __shfl_xor(m, off);
            float l2 = __shfl_xor(l, off);
            float mn = fmaxf(m, m2);
            l = l * __expf(m - mn) + l2 * __expf(m2 - mn);
            m = mn;
        }
        if (lq == 0) {
            int kg = k0b + w * 16 + g * 4 + r;
            m_out[b * HW + kg]  = m;
            il_out[b * HW + kg] = 1.0f / l;
        }
    }
}

// ===========================================================================
// k3_out: out[b,v,q] = sum_k exp(s-m_k)*il_k * V[v,k].
// 512 threads, BQ=128, single barrier/iter, dbuf K + dbuf pad-36 P (LDS
// conflict-free), V + m/il prefetched to regs at iter top.
// grid: 1-D 256 blocks, id&7 = batch.
// ===========================================================================
extern "C" __global__ void __launch_bounds__(512, 2)
k3_out(const short* __restrict__ KTh, const short* __restrict__ KTl,
       const short* __restrict__ QTh, const short* __restrict__ QTl,
       const short* __restrict__ V2,
       const float* __restrict__ m_in, const float* __restrict__ il_in,
       float* __restrict__ out)
{
    __shared__ __attribute__((aligned(16))) short KH[2][32][256];
    __shared__ __attribute__((aligned(16))) short KL[2][32][256];
    __shared__ __attribute__((aligned(16))) short PH[2][128][36];
    __shared__ __attribute__((aligned(16))) short PL[2][128][36];

    const int id   = blockIdx.x;
    const int b    = id & 7;
    const int q0   = (id >> 3) * 128;
    const int t    = threadIdx.x;
    const int lane = t & 63;
    const int w    = t >> 6;        // 0..7
    const int g    = lane >> 4;
    const int lq   = lane & 15;
    const int g2   = lane >> 5;
    const int l32  = lane & 31;
    const int wv   = w >> 1;        // v quarter for PV
    const int wq2  = w & 1;         // q half for PV

    // Q fragments resident in registers (this wave's 16 q-columns)
    bf16x8 qh[8], ql[8];
    {
        const int qrow = q0 + w * 16 + lq;
        const char* rh = (const char*)QTh + ((size_t)b * HW + qrow) * 512;
        const char* rl = (const char*)QTl + ((size_t)b * HW + qrow) * 512;
        const int swz = (lq & 7) << 4;
        #pragma unroll
        for (int ds = 0; ds < 8; ++ds) {
            int cb = (64 * ds + 16 * g) ^ swz;
            qh[ds] = *(const bf16x8*)(rh + cb);
            ql[ds] = *(const bf16x8*)(rl + cb);
        }
    }

    const char* khbase = (const char*)KTh + (size_t)b * HW * 512;
    const char* klbase = (const char*)KTl + (size_t)b * HW * 512;
    auto stage = [&](int bi, int k0a) {
        #pragma unroll
        for (int j = 0; j < 2; ++j) {
            int c = (j << 3) + w;              // 0..15 chunks of 1 KB
            int o = c * 1024;
            gload16(khbase + (size_t)k0a * 512 + o + lane * 16,
                    (char*)&KH[bi][0][0] + o);
            gload16(klbase + (size_t)k0a * 512 + o + lane * 16,
                    (char*)&KL[bi][0][0] + o);
        }
    };

    f32x16 acc[2][2];
    #pragma unroll
    for (int i = 0; i < 2; ++i)
        #pragma unroll
        for (int j = 0; j < 2; ++j)
            #pragma unroll
            for (int e = 0; e < 16; ++e) acc[i][j][e] = 0.0f;

    const float* mB  = m_in  + b * HW;
    const float* ilB = il_in + b * HW;

    stage(0, 0);
    __syncthreads();

    for (int it = 0; it < 128; ++it) {
        const int cur = it & 1;
        const int k0  = it * 32;

        // ---- prefetches: next K tile -> LDS; V frags + m/il -> regs ----
        if (it + 1 < 128) stage(cur ^ 1, k0 + 32);

        f32x4 mv[2], iv[2];
        #pragma unroll
        for (int kt = 0; kt < 2; ++kt) {
            mv[kt] = *(const f32x4*)&mB[k0 + kt * 16 + g * 4];
            iv[kt] = *(const f32x4*)&ilB[k0 + kt * 16 + g * 4];
        }

        bf16x8 vfh[2][2], vfl[2][2];
        #pragma unroll
        for (int kc = 0; kc < 2; ++kc) {
            const int seg = (k0 >> 3) + kc * 2 + g2;
            #pragma unroll
            for (int mt = 0; mt < 2; ++mt) {
                const int v = wv * 64 + mt * 32 + l32;
                const short* vp = V2 + (((size_t)b * 512 + seg) * DIM + v) * 16;
                vfh[kc][mt] = *(const bf16x8*)(vp);
                vfl[kc][mt] = *(const bf16x8*)(vp + 8);
            }
        }

        // ---- S^T (bitwise identical chain to k3_stats) ----
        f32x4 sacc[2];
        #pragma unroll
        for (int kt = 0; kt < 2; ++kt) { f32x4 z = {0.f,0.f,0.f,0.f}; sacc[kt] = z; }
        const int swzk = (lq & 7) << 4;    // (kt*16+lq)&7 == lq&7
        const char* ahr0 = (const char*)&KH[cur][lq][0];
        const char* ahr1 = (const char*)&KH[cur][16 + lq][0];
        const char* alr0 = (const char*)&KL[cur][lq][0];
        const char* alr1 = (const char*)&KL[cur][16 + lq][0];
        __builtin_amdgcn_s_setprio(1);
        #pragma unroll
        for (int ds = 0; ds < 8; ++ds) {
            int cb = (64 * ds + 16 * g) ^ swzk;
            {
                bf16x8 ah = *(const bf16x8*)(ahr0 + cb);
                bf16x8 al = *(const bf16x8*)(alr0 + cb);
                sacc[0] = mfma16(ah, qh[ds], sacc[0]);
                sacc[0] = mfma16(ah, ql[ds], sacc[0]);
                sacc[0] = mfma16(al, qh[ds], sacc[0]);
            }
            {
                bf16x8 ah = *(const bf16x8*)(ahr1 + cb);
                bf16x8 al = *(const bf16x8*)(alr1 + cb);
                sacc[1] = mfma16(ah, qh[ds], sacc[1]);
                sacc[1] = mfma16(ah, ql[ds], sacc[1]);
                sacc[1] = mfma16(al, qh[ds], sacc[1]);
            }
        }
        __builtin_amdgcn_s_setprio(0);

        // ---- P = exp(s - m_k) * il_k, split-bf16, write to padded P ----
        {
            const int qc = w * 16 + lq;
            #pragma unroll
            for (int kt = 0; kt < 2; ++kt) {
                s16x4 ph, pl;
                #pragma unroll
                for (int r = 0; r < 4; ++r) {
                    float p = __expf(sacc[kt][r] - mv[kt][r]) * iv[kt][r];
                    short h, l; split_bf16(p, h, l);
                    ph[r] = h; pl[r] = l;
                }
                *(s16x4*)&PH[cur][qc][kt * 16 + g * 4] = ph;
                *(s16x4*)&PL[cur][qc][kt * 16 + g * 4] = pl;
            }
        }

        __syncthreads();   // single barrier: P visible + next K tile landed

        // ---- PV: D[v][q] += V[v][k] * P[k][q], 32x32x16 ----
        __builtin_amdgcn_s_setprio(1);
        #pragma unroll
        for (int kc = 0; kc < 2; ++kc) {
            bf16x8 pbh[2], pbl[2];
            #pragma unroll
            for (int qt = 0; qt < 2; ++qt) {
                const int prow = wq2 * 64 + qt * 32 + l32;
                const short* p0 = &PH[cur][prow][kc * 16 + g2 * 8];
                const short* p1 = &PL[cur][prow][kc * 16 + g2 * 8];
                s16x4 a0 = *(const s16x4*)(p0);
                s16x4 a1 = *(const s16x4*)(p0 + 4);
                s16x4 b0 = *(const s16x4*)(p1);
                s16x4 b1 = *(const s16x4*)(p1 + 4);
                bf16x8 rh, rl;
                #pragma unroll
                for (int e = 0; e < 4; ++e) {
                    rh[e] = a0[e]; rh[4 + e] = a1[e];
                    rl[e] = b0[e]; rl[4 + e] = b1[e];
                }
                pbh[qt] = rh; pbl[qt] = rl;
            }
            #pragma unroll
            for (int mt = 0; mt < 2; ++mt) {
                #pragma unroll
                for (int qt = 0; qt < 2; ++qt) {
                    acc[mt][qt] = mfma32(vfh[kc][mt], pbh[qt], acc[mt][qt]);
                    acc[mt][qt] = mfma32(vfh[kc][mt], pbl[qt], acc[mt][qt]);
                    acc[mt][qt] = mfma32(vfl[kc][mt], pbh[qt], acc[mt][qt]);
                }
            }
        }
        __builtin_amdgcn_s_setprio(0);
    }

    // epilogue: D col q = wq2*64 + qt*32 + l32; row v = wv*64 + mt*32 +
    // (r&3)+8*(r>>2)+4*g2
    float* __restrict__ ob = out + (size_t)b * DIM * HW;
    #pragma unroll
    for (int mt = 0; mt < 2; ++mt)
        #pragma unroll
        for (int qt = 0; qt < 2; ++qt)
            #pragma unroll
            for (int r = 0; r < 16; ++r) {
                int v = wv * 64 + mt * 32 + (r & 3) + 8 * (r >> 2) + 4 * g2;
                int q = q0 + wq2 * 64 + qt * 32 + l32;
                ob[(size_t)v * HW + q] = acc[mt][qt][r];
            }
}

// ===========================================================================
// FALLBACK PATH (round-1 passing kernels, used only if ws too small)
// ===========================================================================
extern "C" __global__ void __launch_bounds__(256, 1)
k_stats(const float* __restrict__ K, const float* __restrict__ Q,
        float* __restrict__ m_out, float* __restrict__ il_out)
{
    __shared__ __attribute__((aligned(16))) short KtH[64][264];
    __shared__ __attribute__((aligned(16))) short KtL[64][264];
    __shared__ __attribute__((aligned(16))) short QtH[32][264];
    __shared__ __attribute__((aligned(16))) short QtL[32][264];

    const int b = blockIdx.y, k0 = blockIdx.x * 64, t = threadIdx.x;
    const int lane = t & 63, w = t >> 6, g = lane >> 4, lq = lane & 15;
    const float* Kb = K + (size_t)b * DIM * HW;
    const float* Qb = Q + (size_t)b * DIM * HW;

    {
        const int kk = t & 63, d0 = t >> 6;
        #pragma unroll 4
        for (int pass = 0; pass < 64; ++pass) {
            int d = d0 + pass * 4;
            float x = Kb[(size_t)d * HW + k0 + kk];
            short h, l; split_bf16(x, h, l);
            KtH[kk][d] = h; KtL[kk][d] = l;
        }
    }
    float mr[4], lr[4];
    #pragma unroll
    for (int r = 0; r < 4; ++r) { mr[r] = -3.0e38f; lr[r] = 0.0f; }

    for (int q0 = 0; q0 < HW; q0 += 32) {
        __syncthreads();
        {
            const int qq = t & 31, d0 = t >> 5;
            #pragma unroll 4
            for (int pass = 0; pass < 32; ++pass) {
                int d = d0 + pass * 8;
                float x = Qb[(size_t)d * HW + q0 + qq];
                short h, l; split_bf16(x, h, l);
                QtH[qq][d] = h; QtL[qq][d] = l;
            }
        }
        __syncthreads();
        #pragma unroll
        for (int qt = 0; qt < 2; ++qt) {
            f32x4 acc = {0.f, 0.f, 0.f, 0.f};
            #pragma unroll
            for (int ds = 0; ds < 8; ++ds) {
                const int dof = ds * 32 + g * 8;
                bf16x8 ah = *(const bf16x8*)&KtH[w * 16 + lq][dof];
                bf16x8 al = *(const bf16x8*)&KtL[w * 16 + lq][dof];
                bf16x8 bh = *(const bf16x8*)&QtH[qt * 16 + lq][dof];
                bf16x8 bl = *(const bf16x8*)&QtL[qt * 16 + lq][dof];
                acc = mfma16(ah, bh, acc);
                acc = mfma16(ah, bl, acc);
                acc = mfma16(al, bh, acc);
            }
            #pragma unroll
            for (int r = 0; r < 4; ++r) {
                float s = acc[r];
                if (s > mr[r]) { lr[r] = lr[r] * __expf(mr[r] - s) + 1.0f; mr[r] = s; }
                else lr[r] += __expf(s - mr[r]);
            }
        }
    }
    #pragma unroll
    for (int r = 0; r < 4; ++r) {
        float m = mr[r], l = lr[r];
        #pragma unroll
        for (int off = 1; off < 16; off <<= 1) {
            float m2 = __shfl_xor(m, off), l2 = __shfl_xor(l, off);
            float mn = fmaxf(m, m2);
            l = l * __expf(m - mn) + l2 * __expf(m2 - mn);
            m = mn;
        }
        if (lq == 0) {
            int kg = k0 + w * 16 + g * 4 + r;
            m_out[b * HW + kg] = m;
            il_out[b * HW + kg] = 1.0f / l;
        }
    }
}

extern "C" __global__ void __launch_bounds__(256, 1)
k_attn_out(const float* __restrict__ K, const float* __restrict__ Q,
           const float* __restrict__ V,
           const float* __restrict__ m_in, const float* __restrict__ il_in,
           float* __restrict__ out)
{
    __shared__ __attribute__((aligned(16))) short QtH[64][264];
    __shared__ __attribute__((aligned(16))) short QtL[64][264];
    __shared__ __attribute__((aligned(16))) short KtH[32][264];
    __shared__ __attribute__((aligned(16))) short KtL[32][264];
    __shared__ __attribute__((aligned(16))) short PtH[64][40];
    __shared__ __attribute__((aligned(16))) short PtL[64][40];

    const int b = blockIdx.y, q0 = blockIdx.x * 64, t = threadIdx.x;
    const int lane = t & 63, w = t >> 6, g = lane >> 4, lq = lane & 15;
    const int g2 = lane >> 5, l32 = lane & 31;
    const float* Kb = K + (size_t)b * DIM * HW;
    const float* Qb = Q + (size_t)b * DIM * HW;
    const float* Vb = V + (size_t)b * DIM * HW;
    const float* mB = m_in + b * HW;
    const float* ilB = il_in + b * HW;

    {
        const int qq = t & 63, d0 = t >> 6;
        #pragma unroll 4
        for (int pass = 0; pass < 64; ++pass) {
            int d = d0 + pass * 4;
            float x = Qb[(size_t)d * HW + q0 + qq];
            short h, l; split_bf16(x, h, l);
            QtH[qq][d] = h; QtL[qq][d] = l;
        }
    }
    f32x16 acc[2][2];
    #pragma unroll
    for (int i = 0; i < 2; ++i)
        #pragma unroll
        for (int j = 0; j < 2; ++j)
            #pragma unroll
            for (int e = 0; e < 16; ++e) acc[i][j][e] = 0.0f;

    for (int k0 = 0; k0 < HW; k0 += 32) {
        __syncthreads();
        {
            const int kk = t & 31, d0 = t >> 5;
            #pragma unroll 4
            for (int pass = 0; pass < 32; ++pass) {
                int d = d0 + pass * 8;
                float x = Kb[(size_t)d * HW + k0 + kk];
                short h, l; split_bf16(x, h, l);
                KtH[kk][d] = h; KtL[kk][d] = l;
            }
        }
        __syncthreads();
        f32x4 sacc[2];
        #pragma unroll
        for (int kt = 0; kt < 2; ++kt) { f32x4 z = {0.f,0.f,0.f,0.f}; sacc[kt] = z; }
        #pragma unroll
        for (int ds = 0; ds < 8; ++ds) {
            const int dof = ds * 32 + g * 8;
            bf16x8 bh = *(const bf16x8*)&QtH[w * 16 + lq][dof];
            bf16x8 bl = *(const bf16x8*)&QtL[w * 16 + lq][dof];
            #pragma unroll
            for (int kt = 0; kt < 2; ++kt) {
                bf16x8 ah = *(const bf16x8*)&KtH[kt * 16 + lq][dof];
                bf16x8 al = *(const bf16x8*)&KtL[kt * 16 + lq][dof];
                sacc[kt] = mfma16(ah, bh, sacc[kt]);
                sacc[kt] = mfma16(ah, bl, sacc[kt]);
                sacc[kt] = mfma16(al, bh, sacc[kt]);
            }
        }
        {
            const int qc = w * 16 + lq;
            #pragma unroll
            for (int kt = 0; kt < 2; ++kt) {
                s16x4 ph, pl;
                #pragma unroll
                for (int r = 0; r < 4; ++r) {
                    int kg = k0 + kt * 16 + g * 4 + r;
                    float p = __expf(sacc[kt][r] - mB[kg]) * ilB[kg];
                    short h, l; split_bf16(p, h, l);
                    ph[r] = h; pl[r] = l;
                }
                *(s16x4*)&PtH[qc][kt * 16 + g * 4] = ph;
                *(s16x4*)&PtL[qc][kt * 16 + g * 4] = pl;
            }
        }
        __syncthreads();
        #pragma unroll
        for (int kc = 0; kc < 2; ++kc) {
            bf16x8 pbh[2], pbl[2];
            #pragma unroll
            for (int qt = 0; qt < 2; ++qt) {
                pbh[qt] = *(const bf16x8*)&PtH[qt * 32 + l32][kc * 16 + g2 * 8];
                pbl[qt] = *(const bf16x8*)&PtL[qt * 32 + l32][kc * 16 + g2 * 8];
            }
            #pragma unroll
            for (int mt = 0; mt < 2; ++mt) {
                const int v = w * 64 + mt * 32 + l32;
                const float* vp = Vb + (size_t)v * HW + k0 + kc * 16 + g2 * 8;
                f32x4 x0 = *(const f32x4*)vp;
                f32x4 x1 = *(const f32x4*)(vp + 4);
                bf16x8 ah, al;
                #pragma unroll
                for (int j = 0; j < 4; ++j) {
                    short h, l;
                    split_bf16(x0[j], h, l); ah[j] = h;     al[j] = l;
                    split_bf16(x1[j], h, l); ah[4 + j] = h; al[4 + j] = l;
                }
                #pragma unroll
                for (int qt = 0; qt < 2; ++qt) {
                    acc[mt][qt] = mfma32(ah, pbh[qt], acc[mt][qt]);
                    acc[mt][qt] = mfma32(ah, pbl[qt], acc[mt][qt]);
                    acc[mt][qt] = mfma32(al, pbh[qt], acc[mt][qt]);
                }
            }
        }
    }
    float* ob = out + (size_t)b * DIM * HW;
    #pragma unroll
    for (int mt = 0; mt < 2; ++mt)
        #pragma unroll
        for (int qt = 0; qt < 2; ++qt)
            #pragma unroll
            for (int r = 0; r < 16; ++r) {
                int v = w * 64 + mt * 32 + (r & 3) + 8 * (r >> 2) + 4 * g2;
                int q = q0 + qt * 32 + l32;
                ob[(size_t)v * HW + q] = acc[mt][qt][r];
            }
}

// ===========================================================================
extern "C" void kernel_launch(void* const* d_in, const int* in_sizes, int n_in,
                              void* d_out, int out_size, void* d_ws, size_t ws_size,
                              hipStream_t stream)
{
    (void)in_sizes; (void)n_in; (void)out_size;
    const float* K = (const float*)d_in[0];
    const float* Q = (const float*)d_in[1];
    const float* V = (const float*)d_in[2];

    char* wsb = (char*)d_ws;
    float* m_ws  = (float*)wsb;
    float* il_ws = m_ws + (size_t)NB * HW;

    const size_t planeElems = (size_t)NB * HW * DIM;   // shorts per plane
    const size_t statsBytes = 262144;
    const size_t need = statsBytes + planeElems * 2 * 4 /*KT,QT hi+lo*/
                                   + planeElems * 2 * 2 /*V2*/;

    dim3 blk(256);
    if (ws_size >= need) {
        short* KTh = (short*)(wsb + statsBytes);
        short* KTl = KTh + planeElems;
        short* QTh = KTl + planeElems;
        short* QTl = QTh + planeElems;
        short* V2  = QTl + planeElems;

        dim3 gT(HW / 16, NB);     // 256 x 8
        pass0_T<<<gT, blk, 0, stream>>>(K, KTh, KTl);
        pass0_T<<<gT, blk, 0, stream>>>(Q, QTh, QTl);
        dim3 gV(DIM, NB);         // 256 x 8
        pass0_V<<<gV, blk, 0, stream>>>(V, V2);

        dim3 blk5(512);
        k3_stats<<<dim3(256), blk5, 0, stream>>>(KTh, KTl, QTh, QTl, m_ws, il_ws);
        k3_out<<<dim3(256), blk5, 0, stream>>>(KTh, KTl, QTh, QTl, V2,
                                               m_ws, il_ws, (float*)d_out);
    } else {
        dim3 gM(64, NB);
        k_stats<<<gM, blk, 0, stream>>>(K, Q, m_ws, il_ws);
        k_attn_out<<<gM, blk, 0, stream>>>(K, Q, V, m_ws, il_ws, (float*)d_out);
    }
}